// Round 2
// baseline (2267.262 us; speedup 1.0000x reference)
//
#include <hip/hip_runtime.h>
#include <math.h>

// Problem: B=4, H=16, S=2048, D=64, fp32.
// scores = (Q@K^T) * 4096  (reference divides by d^-2), softmax, @V.
// Flash-style online softmax. fp32 vector FMA (no fp32 MFMA on CDNA4).
// One block = one (head, 64-query tile). 256 threads = 16x16 logical.

#define S_LEN 2048
#define D_DIM 64
#define BM 64
#define BN 64
#define LSTR 68  // LDS row stride in floats: 16B-aligned (68*4=272B), lane-stride-4 -> 2-way banks (free)

__global__ __launch_bounds__(256, 2)
void attn_fp32_kernel(const float* __restrict__ Q, const float* __restrict__ K,
                      const float* __restrict__ V, float* __restrict__ O) {
  __shared__ float Qs[BM][LSTR];
  __shared__ float Ks[BN][LSTR];
  __shared__ float Vs[BN][LSTR];
  __shared__ float Ps[BM][LSTR];

  const int tid = threadIdx.x;
  const int tx = tid & 15;       // 16 column-group threads
  const int ty = tid >> 4;       // 16 row-group threads
  const int qtile = blockIdx.x;  // 32 q-tiles
  const int head = blockIdx.y;   // 64 (b,h) heads

  const long hoff = (long)head * S_LEN * D_DIM;
  const float* Qh = Q + hoff + (long)qtile * BM * D_DIM;
  const float* Kh = K + hoff;
  const float* Vh = V + hoff;
  float* Oh = O + hoff + (long)qtile * BM * D_DIM;

  // ---- stage Q tile (once): rows ty+16p, cols tx*4 ----
  {
    const int c = tx * 4;
#pragma unroll
    for (int p = 0; p < 4; ++p) {
      const int r = ty + p * 16;
      *(float4*)(&Qs[r][c]) = *(const float4*)(Qh + r * D_DIM + c);
    }
  }

  float m_i[4], l_i[4];
  float4 o_acc[4];
#pragma unroll
  for (int i = 0; i < 4; ++i) {
    m_i[i] = -INFINITY;
    l_i[i] = 0.0f;
    o_acc[i] = make_float4(0.f, 0.f, 0.f, 0.f);
  }

  const float SCALE = 4096.0f;           // 1 / (d^-2), exact power of 2
  const float LOG2E = 1.4426950408889634f;

  for (int kt = 0; kt < S_LEN / BN; ++kt) {
    // ---- stage K,V tiles ----
    {
      const int c = tx * 4;
      const float* Kt = Kh + kt * BN * D_DIM;
      const float* Vt = Vh + kt * BN * D_DIM;
#pragma unroll
      for (int p = 0; p < 4; ++p) {
        const int r = ty + p * 16;
        *(float4*)(&Ks[r][c]) = *(const float4*)(Kt + r * D_DIM + c);
        *(float4*)(&Vs[r][c]) = *(const float4*)(Vt + r * D_DIM + c);
      }
    }
    __syncthreads();

    // ---- matmul1: s[i][j] = Q[ty*4+i][:] . K[tx+16j][:]  (dot-form over d) ----
    float s[4][4];
#pragma unroll
    for (int i = 0; i < 4; ++i)
#pragma unroll
      for (int j = 0; j < 4; ++j) s[i][j] = 0.0f;

#pragma unroll
    for (int d = 0; d < D_DIM; d += 4) {
      float4 q4[4], k4[4];
#pragma unroll
      for (int i = 0; i < 4; ++i) q4[i] = *(const float4*)(&Qs[ty * 4 + i][d]);   // broadcast across tx
#pragma unroll
      for (int j = 0; j < 4; ++j) k4[j] = *(const float4*)(&Ks[tx + 16 * j][d]);  // lane-stride 68: conflict-free
#pragma unroll
      for (int i = 0; i < 4; ++i)
#pragma unroll
        for (int j = 0; j < 4; ++j) {
          s[i][j] += q4[i].x * k4[j].x;
          s[i][j] += q4[i].y * k4[j].y;
          s[i][j] += q4[i].z * k4[j].z;
          s[i][j] += q4[i].w * k4[j].w;
        }
    }

    // ---- online softmax over the 64-wide row (16 lanes x 4 cols each) ----
#pragma unroll
    for (int i = 0; i < 4; ++i) {
#pragma unroll
      for (int j = 0; j < 4; ++j) s[i][j] *= SCALE;

      float rm = fmaxf(fmaxf(s[i][0], s[i][1]), fmaxf(s[i][2], s[i][3]));
#pragma unroll
      for (int off = 8; off >= 1; off >>= 1) rm = fmaxf(rm, __shfl_xor(rm, off));

      const float mnew = fmaxf(m_i[i], rm);
      const float alpha = exp2f((m_i[i] - mnew) * LOG2E);  // m_i=-inf first iter -> 0

      float rs = 0.0f;
#pragma unroll
      for (int j = 0; j < 4; ++j) {
        const float p = exp2f((s[i][j] - mnew) * LOG2E);
        s[i][j] = p;
        rs += p;
      }
#pragma unroll
      for (int off = 8; off >= 1; off >>= 1) rs += __shfl_xor(rs, off);

      l_i[i] = l_i[i] * alpha + rs;
      m_i[i] = mnew;
      o_acc[i].x *= alpha;
      o_acc[i].y *= alpha;
      o_acc[i].z *= alpha;
      o_acc[i].w *= alpha;

      // write P row segment: Ps[ty*4+i][tx + 16j]  (lanes tx contiguous: conflict-free)
      const int m = ty * 4 + i;
      Ps[m][tx]      = s[i][0];
      Ps[m][tx + 16] = s[i][1];
      Ps[m][tx + 32] = s[i][2];
      Ps[m][tx + 48] = s[i][3];
    }
    __syncthreads();

    // ---- matmul2: o[ty*4+i][tx*4..+3] += P[row][k] * V[k][col] ----
#pragma unroll
    for (int k = 0; k < BN; k += 4) {
      float4 p4[4], v4[4];
#pragma unroll
      for (int i = 0; i < 4; ++i) p4[i] = *(const float4*)(&Ps[ty * 4 + i][k]);   // broadcast
#pragma unroll
      for (int kk = 0; kk < 4; ++kk) v4[kk] = *(const float4*)(&Vs[k + kk][tx * 4]);  // 2-way banks: free
#pragma unroll
      for (int i = 0; i < 4; ++i) {
        o_acc[i].x += p4[i].x * v4[0].x + p4[i].y * v4[1].x + p4[i].z * v4[2].x + p4[i].w * v4[3].x;
        o_acc[i].y += p4[i].x * v4[0].y + p4[i].y * v4[1].y + p4[i].z * v4[2].y + p4[i].w * v4[3].y;
        o_acc[i].z += p4[i].x * v4[0].z + p4[i].y * v4[1].z + p4[i].z * v4[2].z + p4[i].w * v4[3].z;
        o_acc[i].w += p4[i].x * v4[0].w + p4[i].y * v4[1].w + p4[i].z * v4[2].w + p4[i].w * v4[3].w;
      }
    }
    __syncthreads();  // protect Ks/Vs for next iteration's staging
  }

  // ---- epilogue: divide by l, store ----
#pragma unroll
  for (int i = 0; i < 4; ++i) {
    const float inv = 1.0f / l_i[i];
    o_acc[i].x *= inv;
    o_acc[i].y *= inv;
    o_acc[i].z *= inv;
    o_acc[i].w *= inv;
    *(float4*)(Oh + (ty * 4 + i) * D_DIM + tx * 4) = o_acc[i];
  }
}

extern "C" void kernel_launch(void* const* d_in, const int* in_sizes, int n_in,
                              void* d_out, int out_size, void* d_ws, size_t ws_size,
                              hipStream_t stream) {
  const float* Q = (const float*)d_in[0];
  const float* K = (const float*)d_in[1];
  const float* V = (const float*)d_in[2];
  float* O = (float*)d_out;

  dim3 grid(S_LEN / BM, 64);  // 32 q-tiles x (B*H=64) heads
  dim3 block(256);
  attn_fp32_kernel<<<grid, block, 0, stream>>>(Q, K, V, O);
}

// Round 3
// 477.500 us; speedup vs baseline: 4.7482x; 4.7482x over previous
//
#include <hip/hip_runtime.h>
#include <math.h>

// B=4,H=16 (NH=64 heads), S=2048, D=64, fp32 in/out.
// scores = (Q@K^T)*4096, softmax, @V.
// Strategy: split fp32 into 3 bf16 planes (RNE), QK^T = 6 bf16 MFMA terms
// (error ~2^-23 rel), PV = bf16(P) x (V_hi + V_mid) (error ~2^-18).
// Prepass writes planes to d_ws; main kernel is flash-style online softmax,
// BM=128 (4 waves x 32 q-rows), BN=64 keys/iter, 16x16x32 bf16 MFMA.
// Fallback: round-0 fp32 vector kernel if ws_size too small.

#define S_LEN 2048
#define D_DIM 64
#define NH 64
#define BM 128
#define BN 64
#define QTILES (S_LEN / BM)   // 16
#define KTILES (S_LEN / BN)   // 32

typedef unsigned short u16;
typedef unsigned int u32;
typedef __attribute__((ext_vector_type(8))) short bf16x8;
typedef __attribute__((ext_vector_type(4))) float f32x4;

__device__ __forceinline__ float fexp2(float x) {
#if __has_builtin(__builtin_amdgcn_exp2f)
  return __builtin_amdgcn_exp2f(x);
#else
  return exp2f(x);
#endif
}

__device__ __forceinline__ u32 bf16_rne_bits(float a) {
  u32 u = __float_as_uint(a);
  return (u + 0x7FFFu + ((u >> 16) & 1u)) >> 16;
}

__device__ __forceinline__ void split3f(float a, u32& h, u32& m, u32& l) {
  u32 u = __float_as_uint(a);
  u32 hb = (u + 0x7FFFu + ((u >> 16) & 1u)) & 0xFFFF0000u;
  float r1 = a - __uint_as_float(hb);
  u32 v = __float_as_uint(r1);
  u32 mb = (v + 0x7FFFu + ((v >> 16) & 1u)) & 0xFFFF0000u;
  float r2 = r1 - __uint_as_float(mb);
  u32 w = __float_as_uint(r2);
  u32 lb = (w + 0x7FFFu + ((w >> 16) & 1u));
  h = hb >> 16; m = mb >> 16; l = lb >> 16;
}

__device__ __forceinline__ void split2f(float a, u32& h, u32& m) {
  u32 u = __float_as_uint(a);
  u32 hb = (u + 0x7FFFu + ((u >> 16) & 1u)) & 0xFFFF0000u;
  float r1 = a - __uint_as_float(hb);
  u32 v = __float_as_uint(r1);
  h = hb >> 16;
  m = (v + 0x7FFFu + ((v >> 16) & 1u)) >> 16;
}

// ---- Prepass 1: elementwise fp32 -> 3 bf16 planes (for Q and K) ----
__global__ void split3_kernel(const float* __restrict__ src, u16* __restrict__ ph,
                              u16* __restrict__ pm, u16* __restrict__ pl) {
  size_t i4 = ((size_t)blockIdx.x * 256 + threadIdx.x) * 4;
  float4 v = *(const float4*)(src + i4);
  u32 h0, m0, l0, h1, m1, l1, h2, m2, l2, h3, m3, l3;
  split3f(v.x, h0, m0, l0);
  split3f(v.y, h1, m1, l1);
  split3f(v.z, h2, m2, l2);
  split3f(v.w, h3, m3, l3);
  *(uint2*)(ph + i4) = make_uint2(h0 | (h1 << 16), h2 | (h3 << 16));
  *(uint2*)(pm + i4) = make_uint2(m0 | (m1 << 16), m2 | (m3 << 16));
  *(uint2*)(pl + i4) = make_uint2(l0 | (l1 << 16), l2 | (l3 << 16));
}

// ---- Prepass 2: V -> transposed bf16 planes Vt[h][d][s] (hi, mid) ----
__global__ void vprep_kernel(const float* __restrict__ V, u16* __restrict__ Vh,
                             u16* __restrict__ Vm) {
  __shared__ float Vf[64 * 65];
  const int tid = threadIdx.x;
  const int kt = blockIdx.x, h = blockIdx.y;
  const float* Vt0 = V + ((size_t)h * S_LEN + kt * 64) * 64;
  const int tx = tid & 15, ty = tid >> 4;
#pragma unroll
  for (int p = 0; p < 4; ++p) {
    int r = ty + 16 * p;
    float4 v = *(const float4*)(Vt0 + r * 64 + tx * 4);
    Vf[r * 65 + 4 * tx + 0] = v.x;
    Vf[r * 65 + 4 * tx + 1] = v.y;
    Vf[r * 65 + 4 * tx + 2] = v.z;
    Vf[r * 65 + 4 * tx + 3] = v.w;
  }
  __syncthreads();
  const int c8 = tid & 7, dr = tid >> 3;
#pragma unroll
  for (int p = 0; p < 2; ++p) {
    int d = dr + 32 * p;
    u32 hw[4], mw[4];
#pragma unroll
    for (int i = 0; i < 4; ++i) {
      float a0 = Vf[(8 * c8 + 2 * i) * 65 + d];
      float a1 = Vf[(8 * c8 + 2 * i + 1) * 65 + d];
      u32 ah, am, bh, bm;
      split2f(a0, ah, am);
      split2f(a1, bh, bm);
      hw[i] = ah | (bh << 16);
      mw[i] = am | (bm << 16);
    }
    size_t o = ((size_t)h * 64 + d) * S_LEN + (size_t)kt * 64 + 8 * c8;
    *(uint4*)(Vh + o) = make_uint4(hw[0], hw[1], hw[2], hw[3]);
    *(uint4*)(Vm + o) = make_uint4(mw[0], mw[1], mw[2], mw[3]);
  }
}

// ---- Main fused attention kernel (bf16-split MFMA) ----
// LDS layout (ushort units), all rows stride 72 ush (144 B), dword-swizzled:
//   K planes (h/m/l): 3 x 64x72   Vt planes (h/m): 2 x 64x72   Ps: 128x72
#define KS0 0
#define KS1 4608
#define KS2 9216
#define VT0 13824
#define VT1 18432
#define PSO 23040
#define LDS_USH 32256  // 64512 B

__global__ __launch_bounds__(256, 2)
void attn_mfma(const u16* __restrict__ Qh, const u16* __restrict__ Qm,
               const u16* __restrict__ Ql, const u16* __restrict__ Kh,
               const u16* __restrict__ Km, const u16* __restrict__ Kl,
               const u16* __restrict__ Vh, const u16* __restrict__ Vm,
               float* __restrict__ O) {
  __shared__ __align__(16) u16 lds[LDS_USH];

  const int tid = threadIdx.x;
  const int lane = tid & 63;
  const int wv = tid >> 6;
  const int c = lane & 15;   // col within 16 (MFMA n / A-row m)
  const int g = lane >> 4;   // quad
  const int qtile = blockIdx.x;
  const int h = blockIdx.y;

  const float SC = 4096.0f * 1.4426950408889634f;  // scale * log2(e)

  // ---- preload Q A-frags (registers, whole kernel) ----
  bf16x8 aqh[2][2], aqm[2][2], aql[2][2];
#pragma unroll
  for (int m = 0; m < 2; ++m) {
    int qrow = qtile * BM + wv * 32 + m * 16 + c;
    size_t qbase = ((size_t)h * S_LEN + qrow) * 64 + g * 8;
#pragma unroll
    for (int ks = 0; ks < 2; ++ks) {
      aqh[m][ks] = *(const bf16x8*)(Qh + qbase + ks * 32);
      aqm[m][ks] = *(const bf16x8*)(Qm + qbase + ks * 32);
      aql[m][ks] = *(const bf16x8*)(Ql + qbase + ks * 32);
    }
  }

  f32x4 Oacc[2][4];
  float mrow[2][4], lrow[2][4];
#pragma unroll
  for (int m = 0; m < 2; ++m)
#pragma unroll
    for (int t = 0; t < 4; ++t) Oacc[m][t] = (f32x4){0.f, 0.f, 0.f, 0.f};
#pragma unroll
  for (int m = 0; m < 2; ++m)
#pragma unroll
    for (int r = 0; r < 4; ++r) { mrow[m][r] = -INFINITY; lrow[m][r] = 0.f; }

  // staging roles
  const int tx8 = tid & 7, rid = tid >> 3;
  // lane part of swizzled frag-read offset (ushorts): row*72 + (4g ^ 4(c&3))*2
  const int fragoff = ((4 * g) ^ (4 * (c & 3))) * 2;

  for (int kt = 0; kt < KTILES; ++kt) {
    __syncthreads();
    // ---- stage K (3 planes) and Vt (2 planes), bf16, swizzled b128 writes ----
    {
      size_t gK = ((size_t)h * S_LEN + (size_t)kt * 64) * 64 + tx8 * 8;
      size_t gV = (size_t)h * 64 * S_LEN + (size_t)kt * 64 + tx8 * 8;
#pragma unroll
      for (int p = 0; p < 2; ++p) {
        int r = rid + 32 * p;
        int li = r * 72 + ((4 * tx8) ^ ((r & 3) << 2)) * 2;
        *(uint4*)&lds[KS0 + li] = *(const uint4*)(Kh + gK + (size_t)r * 64);
        *(uint4*)&lds[KS1 + li] = *(const uint4*)(Km + gK + (size_t)r * 64);
        *(uint4*)&lds[KS2 + li] = *(const uint4*)(Kl + gK + (size_t)r * 64);
        *(uint4*)&lds[VT0 + li] = *(const uint4*)(Vh + gV + (size_t)r * S_LEN);
        *(uint4*)&lds[VT1 + li] = *(const uint4*)(Vm + gV + (size_t)r * S_LEN);
      }
    }
    __syncthreads();

    // ---- matmul1: S = Q K^T via 6 split MFMAs ----
    f32x4 S[2][4];
#pragma unroll
    for (int m = 0; m < 2; ++m)
#pragma unroll
      for (int t = 0; t < 4; ++t) S[m][t] = (f32x4){0.f, 0.f, 0.f, 0.f};

#pragma unroll
    for (int ks = 0; ks < 2; ++ks) {
#pragma unroll
      for (int t = 0; t < 4; ++t) {
        int rb = (16 * t + c) * 72 + fragoff + ks * 32;
        bf16x8 bh = *(const bf16x8*)&lds[KS0 + rb];
        bf16x8 bm = *(const bf16x8*)&lds[KS1 + rb];
        bf16x8 bl = *(const bf16x8*)&lds[KS2 + rb];
#pragma unroll
        for (int m = 0; m < 2; ++m) {
          S[m][t] = __builtin_amdgcn_mfma_f32_16x16x32_bf16(aqh[m][ks], bh, S[m][t], 0, 0, 0);
          S[m][t] = __builtin_amdgcn_mfma_f32_16x16x32_bf16(aqh[m][ks], bm, S[m][t], 0, 0, 0);
          S[m][t] = __builtin_amdgcn_mfma_f32_16x16x32_bf16(aqm[m][ks], bh, S[m][t], 0, 0, 0);
          S[m][t] = __builtin_amdgcn_mfma_f32_16x16x32_bf16(aqm[m][ks], bm, S[m][t], 0, 0, 0);
          S[m][t] = __builtin_amdgcn_mfma_f32_16x16x32_bf16(aqh[m][ks], bl, S[m][t], 0, 0, 0);
          S[m][t] = __builtin_amdgcn_mfma_f32_16x16x32_bf16(aql[m][ks], bh, S[m][t], 0, 0, 0);
        }
      }
    }

    // ---- online softmax (rows = 4g+reg within each m-tile) + P write ----
#pragma unroll
    for (int m = 0; m < 2; ++m) {
#pragma unroll
      for (int t = 0; t < 4; ++t) S[m][t] = S[m][t] * SC;
#pragma unroll
      for (int reg = 0; reg < 4; ++reg) {
        float rm = fmaxf(fmaxf(S[m][0][reg], S[m][1][reg]),
                         fmaxf(S[m][2][reg], S[m][3][reg]));
        rm = fmaxf(rm, __shfl_xor(rm, 1));
        rm = fmaxf(rm, __shfl_xor(rm, 2));
        rm = fmaxf(rm, __shfl_xor(rm, 4));
        rm = fmaxf(rm, __shfl_xor(rm, 8));
        float mnew = fmaxf(mrow[m][reg], rm);
        float alpha = fexp2(mrow[m][reg] - mnew);
        float rs = 0.f;
#pragma unroll
        for (int t = 0; t < 4; ++t) {
          float p = fexp2(S[m][t][reg] - mnew);
          S[m][t][reg] = p;
          rs += p;
        }
        rs += __shfl_xor(rs, 1);
        rs += __shfl_xor(rs, 2);
        rs += __shfl_xor(rs, 4);
        rs += __shfl_xor(rs, 8);
        lrow[m][reg] = lrow[m][reg] * alpha + rs;
        mrow[m][reg] = mnew;
#pragma unroll
        for (int nt = 0; nt < 4; ++nt) Oacc[m][nt][reg] *= alpha;
        // P write: row rq (rq&3 == reg), swizzled dword col
        int rq = wv * 32 + m * 16 + 4 * g + reg;
#pragma unroll
        for (int t = 0; t < 4; ++t) {
          int cdp = (8 * t + (c >> 1)) ^ (reg << 2);
          lds[PSO + rq * 72 + cdp * 2 + (c & 1)] = (u16)bf16_rne_bits(S[m][t][reg]);
        }
      }
    }
    // no barrier: each wave reads back only its own P rows

    // ---- matmul2: O += P V (V split hi/mid) ----
    bf16x8 ap[2][2];
#pragma unroll
    for (int m = 0; m < 2; ++m) {
      int rq = wv * 32 + m * 16 + c;
#pragma unroll
      for (int ks = 0; ks < 2; ++ks)
        ap[m][ks] = *(const bf16x8*)&lds[PSO + rq * 72 + fragoff + ks * 32];
    }
#pragma unroll
    for (int ks = 0; ks < 2; ++ks) {
#pragma unroll
      for (int nt = 0; nt < 4; ++nt) {
        int rb = (16 * nt + c) * 72 + fragoff + ks * 32;
        bf16x8 bvh = *(const bf16x8*)&lds[VT0 + rb];
        bf16x8 bvm = *(const bf16x8*)&lds[VT1 + rb];
#pragma unroll
        for (int m = 0; m < 2; ++m) {
          Oacc[m][nt] = __builtin_amdgcn_mfma_f32_16x16x32_bf16(ap[m][ks], bvh, Oacc[m][nt], 0, 0, 0);
          Oacc[m][nt] = __builtin_amdgcn_mfma_f32_16x16x32_bf16(ap[m][ks], bvm, Oacc[m][nt], 0, 0, 0);
        }
      }
    }
  }

  // ---- epilogue: divide by l, store ----
#pragma unroll
  for (int m = 0; m < 2; ++m) {
    float inv[4];
#pragma unroll
    for (int reg = 0; reg < 4; ++reg) inv[reg] = 1.0f / lrow[m][reg];
#pragma unroll
    for (int nt = 0; nt < 4; ++nt)
#pragma unroll
      for (int reg = 0; reg < 4; ++reg) {
        int row = qtile * BM + wv * 32 + m * 16 + 4 * g + reg;
        O[((size_t)h * S_LEN + row) * 64 + 16 * nt + c] = Oacc[m][nt][reg] * inv[reg];
      }
  }
}

// ---- Fallback: round-0 fp32 vector kernel (used if ws too small) ----
#define LSTR 68
__global__ __launch_bounds__(256, 2)
void attn_fp32_kernel(const float* __restrict__ Q, const float* __restrict__ K,
                      const float* __restrict__ V, float* __restrict__ O) {
  __shared__ float Qs[64][LSTR];
  __shared__ float Ks[64][LSTR];
  __shared__ float Vs[64][LSTR];
  __shared__ float Ps[64][LSTR];
  const int tid = threadIdx.x;
  const int tx = tid & 15, ty = tid >> 4;
  const int qtile = blockIdx.x, head = blockIdx.y;
  const long hoff = (long)head * S_LEN * D_DIM;
  const float* Qp = Q + hoff + (long)qtile * 64 * D_DIM;
  const float* Kp = K + hoff;
  const float* Vp = V + hoff;
  float* Op = O + hoff + (long)qtile * 64 * D_DIM;
  {
    const int cc = tx * 4;
#pragma unroll
    for (int p = 0; p < 4; ++p) {
      const int r = ty + p * 16;
      *(float4*)(&Qs[r][cc]) = *(const float4*)(Qp + r * D_DIM + cc);
    }
  }
  float m_i[4], l_i[4];
  float4 o_acc[4];
#pragma unroll
  for (int i = 0; i < 4; ++i) {
    m_i[i] = -INFINITY; l_i[i] = 0.0f;
    o_acc[i] = make_float4(0.f, 0.f, 0.f, 0.f);
  }
  const float SCALE = 4096.0f;
  const float LOG2E = 1.4426950408889634f;
  for (int kt = 0; kt < S_LEN / 64; ++kt) {
    {
      const int cc = tx * 4;
      const float* Kt = Kp + kt * 64 * D_DIM;
      const float* Vt = Vp + kt * 64 * D_DIM;
#pragma unroll
      for (int p = 0; p < 4; ++p) {
        const int r = ty + p * 16;
        *(float4*)(&Ks[r][cc]) = *(const float4*)(Kt + r * D_DIM + cc);
        *(float4*)(&Vs[r][cc]) = *(const float4*)(Vt + r * D_DIM + cc);
      }
    }
    __syncthreads();
    float s[4][4];
#pragma unroll
    for (int i = 0; i < 4; ++i)
#pragma unroll
      for (int j = 0; j < 4; ++j) s[i][j] = 0.0f;
#pragma unroll
    for (int d = 0; d < D_DIM; d += 4) {
      float4 q4[4], k4[4];
#pragma unroll
      for (int i = 0; i < 4; ++i) q4[i] = *(const float4*)(&Qs[ty * 4 + i][d]);
#pragma unroll
      for (int j = 0; j < 4; ++j) k4[j] = *(const float4*)(&Ks[tx + 16 * j][d]);
#pragma unroll
      for (int i = 0; i < 4; ++i)
#pragma unroll
        for (int j = 0; j < 4; ++j) {
          s[i][j] += q4[i].x * k4[j].x; s[i][j] += q4[i].y * k4[j].y;
          s[i][j] += q4[i].z * k4[j].z; s[i][j] += q4[i].w * k4[j].w;
        }
    }
#pragma unroll
    for (int i = 0; i < 4; ++i) {
#pragma unroll
      for (int j = 0; j < 4; ++j) s[i][j] *= SCALE;
      float rm = fmaxf(fmaxf(s[i][0], s[i][1]), fmaxf(s[i][2], s[i][3]));
#pragma unroll
      for (int off = 8; off >= 1; off >>= 1) rm = fmaxf(rm, __shfl_xor(rm, off));
      const float mnew = fmaxf(m_i[i], rm);
      const float alpha = exp2f((m_i[i] - mnew) * LOG2E);
      float rs = 0.0f;
#pragma unroll
      for (int j = 0; j < 4; ++j) {
        const float p = exp2f((s[i][j] - mnew) * LOG2E);
        s[i][j] = p; rs += p;
      }
#pragma unroll
      for (int off = 8; off >= 1; off >>= 1) rs += __shfl_xor(rs, off);
      l_i[i] = l_i[i] * alpha + rs;
      m_i[i] = mnew;
      o_acc[i].x *= alpha; o_acc[i].y *= alpha; o_acc[i].z *= alpha; o_acc[i].w *= alpha;
      const int mm = ty * 4 + i;
      Ps[mm][tx] = s[i][0]; Ps[mm][tx + 16] = s[i][1];
      Ps[mm][tx + 32] = s[i][2]; Ps[mm][tx + 48] = s[i][3];
    }
    __syncthreads();
#pragma unroll
    for (int k = 0; k < 64; k += 4) {
      float4 p4[4], v4[4];
#pragma unroll
      for (int i = 0; i < 4; ++i) p4[i] = *(const float4*)(&Ps[ty * 4 + i][k]);
#pragma unroll
      for (int kk = 0; kk < 4; ++kk) v4[kk] = *(const float4*)(&Vs[k + kk][tx * 4]);
#pragma unroll
      for (int i = 0; i < 4; ++i) {
        o_acc[i].x += p4[i].x * v4[0].x + p4[i].y * v4[1].x + p4[i].z * v4[2].x + p4[i].w * v4[3].x;
        o_acc[i].y += p4[i].x * v4[0].y + p4[i].y * v4[1].y + p4[i].z * v4[2].y + p4[i].w * v4[3].y;
        o_acc[i].z += p4[i].x * v4[0].z + p4[i].y * v4[1].z + p4[i].z * v4[2].z + p4[i].w * v4[3].z;
        o_acc[i].w += p4[i].x * v4[0].w + p4[i].y * v4[1].w + p4[i].z * v4[2].w + p4[i].w * v4[3].w;
      }
    }
    __syncthreads();
  }
#pragma unroll
  for (int i = 0; i < 4; ++i) {
    const float inv = 1.0f / l_i[i];
    o_acc[i].x *= inv; o_acc[i].y *= inv; o_acc[i].z *= inv; o_acc[i].w *= inv;
    *(float4*)(Op + (ty * 4 + i) * D_DIM + tx * 4) = o_acc[i];
  }
}

extern "C" void kernel_launch(void* const* d_in, const int* in_sizes, int n_in,
                              void* d_out, int out_size, void* d_ws, size_t ws_size,
                              hipStream_t stream) {
  const float* Q = (const float*)d_in[0];
  const float* K = (const float*)d_in[1];
  const float* V = (const float*)d_in[2];
  float* O = (float*)d_out;

  const size_t P = (size_t)NH * S_LEN * D_DIM;  // 8388608 elements per plane
  const size_t need = 8 * P * sizeof(u16);      // 134217728 bytes

  if (ws_size >= need) {
    u16* w = (u16*)d_ws;
    u16 *Qh = w, *Qm = w + P, *Ql = w + 2 * P;
    u16 *Kh = w + 3 * P, *Km = w + 4 * P, *Kl = w + 5 * P;
    u16 *Vh = w + 6 * P, *Vm = w + 7 * P;

    split3_kernel<<<8192, 256, 0, stream>>>(Q, Qh, Qm, Ql);
    split3_kernel<<<8192, 256, 0, stream>>>(K, Kh, Km, Kl);
    vprep_kernel<<<dim3(KTILES, NH), 256, 0, stream>>>(V, Vh, Vm);
    attn_mfma<<<dim3(QTILES, NH), 256, 0, stream>>>(Qh, Qm, Ql, Kh, Km, Kl, Vh, Vm, O);
  } else {
    attn_fp32_kernel<<<dim3(S_LEN / 64, NH), 256, 0, stream>>>(Q, K, V, O);
  }
}